// Round 6
// baseline (458.194 us; speedup 1.0000x reference)
//
#include <hip/hip_runtime.h>
#include <math.h>

// Problem constants (fixed by the reference's setup_inputs)
constexpr int N_  = 2;
constexpr int E_  = 16;
constexpr int C_  = 32;
constexpr int V_  = 48 * 160 * 160;   // 1,228,800 voxels per batch
constexpr int V4_ = V_ / 4;           // 307,200 float4 groups per batch
constexpr int BLK = 256;

constexpr float DELTA_VAR  = 0.5f;
constexpr float DELTA_DIST = 2.0f;
constexpr float GAMMA      = 0.001f;

// 8-way split accumulators (atomic decontention).
// ws floats: [0,8192) gsumT8[k][n][e][c] ; [8192,8704) gcnt8[k][n][c] ;
//            [8704,8720) gvar8[k][n] ; [8720] sums ticket ; [8721] var ticket ;
//            [8724,10004) mu[n][c][MUP]
constexpr int NCOPY     = 8;
constexpr int MUP       = 20;
constexpr int WS_SUMT   = 0;
constexpr int WS_CNT    = WS_SUMT + NCOPY * N_ * E_ * C_;   // 8192
constexpr int WS_VAR    = WS_CNT  + NCOPY * N_ * C_;        // 8704
constexpr int WS_TK1    = WS_VAR  + NCOPY * N_;             // 8720 (sums)
constexpr int WS_TK2    = WS_TK1 + 1;                       // 8721 (var)
constexpr int WS_MU     = WS_TK1 + 4;                       // 8724
constexpr int WS_ZERO   = WS_MU;                            // memset range (mu overwritten)

constexpr int GS_TOT = 600 * N_;      // 1200 sums blocks (ticket target)
constexpr int GV     = 1024;          // variance grid: persistent, 4 blocks/CU

using short8 = __attribute__((ext_vector_type(8))) short;
using f32x4  = __attribute__((ext_vector_type(4))) float;

__device__ __forceinline__ unsigned short f2bf(float f) {
    unsigned u = __float_as_uint(f);
    return (unsigned short)((u + 0x7FFFu + ((u >> 16) & 1u)) >> 16);
}
__device__ __forceinline__ unsigned packlab(int4 t) {
    return (unsigned)t.x | ((unsigned)t.y << 8) | ((unsigned)t.z << 16) | ((unsigned)t.w << 24);
}
// agent-scope (device-coherent) load: reads values written by other blocks'
// device-scope atomics in the SAME kernel, bypassing possibly-stale L1/L2.
__device__ __forceinline__ float gload(const float* p) {
    return __hip_atomic_load(p, __ATOMIC_RELAXED, __HIP_MEMORY_SCOPE_AGENT);
}

// ---------------------------------------------------------------------------
// Kernel 1: MFMA segmented sums + counts — DIRECT-LOAD version. No staging
// LDS, no main-loop barriers: lane (myc,quad) loads its A-fragment slice
// (row e=myc, 8 consecutive voxels) straight from global as 2 float4s and
// converts f32->bf16 in-register. 16 K-steps per wave, FULLY UNROLLED with
// ping-pong register sets (all compile-time indices — no scratch).
// grid = (600, N), block = 256 (4 waves), 2048 voxels per block.
// Epilogue: cross-wave LDS reduce + 8-way split atomics; LAST block (ticket)
// builds the mu table into ws.
// ---------------------------------------------------------------------------
__global__ __launch_bounds__(BLK) void sums_mfma(
    const float4* __restrict__ x4, const int4* __restrict__ t4,
    float* __restrict__ ws)
{
    __shared__ float s_red[2176];   // 8704 B: 2048 sums + 128 counts
    __shared__ unsigned s_flag;

    const int n     = blockIdx.y;
    const int gtile = blockIdx.x * 2048;
    const int tid   = threadIdx.x;
    const int lane  = tid & 63;
    const int wid   = tid >> 6;
    const int myc   = lane & 15;
    const int quad  = lane >> 4;

    const short one = (short)0x3F80;
    short8 A_ones = {one, one, one, one, one, one, one, one};

    f32x4 acc_lo = {0.f,0.f,0.f,0.f}, acc_hi = {0.f,0.f,0.f,0.f};
    f32x4 cnt_lo = {0.f,0.f,0.f,0.f}, cnt_hi = {0.f,0.f,0.f,0.f};

    const float4* __restrict__ xrow = x4 + (size_t)(n * E_ + myc) * V4_;
    const int4*   __restrict__ t4n  = t4 + (size_t)n * V4_;
    // float4 index of this lane's step-0 slice (8 voxels of row myc)
    const int base4 = (gtile + wid * 512 + quad * 8) >> 2;

#define LOADS(X0, X1, P, Q, s) do {            \
        X0 = xrow[base4 + (s) * 8];            \
        X1 = xrow[base4 + (s) * 8 + 1];        \
        P  = t4n [base4 + (s) * 8];            \
        Q  = t4n [base4 + (s) * 8 + 1];        \
    } while (0)

#define STEP(X0, X1, P, Q) do {                                              \
        short8 A;                                                            \
        A[0] = (short)f2bf(X0.x); A[1] = (short)f2bf(X0.y);                  \
        A[2] = (short)f2bf(X0.z); A[3] = (short)f2bf(X0.w);                  \
        A[4] = (short)f2bf(X1.x); A[5] = (short)f2bf(X1.y);                  \
        A[6] = (short)f2bf(X1.z); A[7] = (short)f2bf(X1.w);                  \
        const unsigned la = packlab(P), lb2 = packlab(Q);                    \
        short8 Blo, Bhi;                                                     \
        _Pragma("unroll")                                                    \
        for (int j = 0; j < 4; ++j) {                                        \
            const int c0 = (la  >> (8 * j)) & 255;                           \
            const int c1 = (lb2 >> (8 * j)) & 255;                           \
            Blo[j]     = (c0 == myc)      ? one : (short)0;                  \
            Bhi[j]     = (c0 == myc + 16) ? one : (short)0;                  \
            Blo[4 + j] = (c1 == myc)      ? one : (short)0;                  \
            Bhi[4 + j] = (c1 == myc + 16) ? one : (short)0;                  \
        }                                                                    \
        acc_lo = __builtin_amdgcn_mfma_f32_16x16x32_bf16(A,      Blo, acc_lo, 0, 0, 0); \
        acc_hi = __builtin_amdgcn_mfma_f32_16x16x32_bf16(A,      Bhi, acc_hi, 0, 0, 0); \
        cnt_lo = __builtin_amdgcn_mfma_f32_16x16x32_bf16(A_ones, Blo, cnt_lo, 0, 0, 0); \
        cnt_hi = __builtin_amdgcn_mfma_f32_16x16x32_bf16(A_ones, Bhi, cnt_hi, 0, 0, 0); \
    } while (0)

    float4 X0a, X1a, X0b, X1b;
    int4   Pa, Qa, Pb, Qb;
    LOADS(X0a, X1a, Pa, Qa, 0);
    LOADS(X0b, X1b, Pb, Qb, 1);

    #pragma unroll
    for (int s = 0; s < 16; s += 2) {
        STEP(X0a, X1a, Pa, Qa);
        if (s + 2 < 16) LOADS(X0a, X1a, Pa, Qa, s + 2);
        STEP(X0b, X1b, Pb, Qb);
        if (s + 3 < 16) LOADS(X0b, X1b, Pb, Qb, s + 3);
    }
#undef LOADS
#undef STEP

    // ---- epilogue: cross-wave LDS reduce, then 512 (+32) atomics per BLOCK
    #pragma unroll
    for (int r = 0; r < 4; ++r) {
        s_red[wid * 512 + lane * 8 + r]     = acc_lo[r];
        s_red[wid * 512 + lane * 8 + 4 + r] = acc_hi[r];
    }
    if (quad == 0) {
        s_red[2048 + wid * 32 + myc]      = cnt_lo[0];
        s_red[2048 + wid * 32 + myc + 16] = cnt_hi[0];
    }
    __syncthreads();

    const int kc = blockIdx.x & (NCOPY - 1);
    float* gsumT = ws + WS_SUMT + kc * (N_ * E_ * C_);
    float* gcntk = ws + WS_CNT  + kc * (N_ * C_);
    #pragma unroll
    for (int u = 0; u < 2; ++u) {
        const int combo = tid * 2 + u;              // 0..511
        const int l = combo >> 3, k = combo & 7;
        const int e = (l >> 4) * 4 + (k & 3);
        const int c = (l & 15) + 16 * (k >> 2);
        const float v = s_red[combo] + s_red[512 + combo]
                      + s_red[1024 + combo] + s_red[1536 + combo];
        unsafeAtomicAdd(&gsumT[(n * E_ + e) * C_ + c], v);
    }
    if (tid < C_) {
        const float v = s_red[2048 + tid] + s_red[2048 + 32 + tid]
                      + s_red[2048 + 64 + tid] + s_red[2048 + 96 + tid];
        unsafeAtomicAdd(&gcntk[n * C_ + tid], v);
    }

    // ---- ticket: LAST block builds the mu table (means + hinge weights)
    __threadfence();                 // my atomics globally visible
    __syncthreads();
    if (tid == 0) {
        unsigned* tk = (unsigned*)(ws + WS_TK1);
        s_flag = (atomicAdd(tk, 1u) == (unsigned)(GS_TOT - 1)) ? 1u : 0u;
    }
    __syncthreads();
    if (s_flag) {
        __threadfence();             // acquire: other blocks' atomics
        const float* gS = ws + WS_SUMT;
        const float* gC = ws + WS_CNT;
        float*       mu = ws + WS_MU;
        for (int i = tid; i < N_ * C_ * E_; i += BLK) {
            const int n2 = i >> 9;            // C_*E_ = 512
            const int r  = i & 511;
            const int c  = r >> 4, e = r & 15;
            float s = 0.f, cc = 0.f;
            #pragma unroll
            for (int k = 0; k < NCOPY; ++k) {
                s  += gload(&gS[k * (N_ * E_ * C_) + (n2 * E_ + e) * C_ + c]);
                cc += gload(&gC[k * (N_ * C_) + n2 * C_ + c]);
            }
            mu[(n2 * C_ + c) * MUP + e] = s / cc;
            if (e == 0) mu[(n2 * C_ + c) * MUP + 16] = 1.0f / (cc * (float)C_);
        }
    }
}

// ---------------------------------------------------------------------------
// Kernel 2: variance — R5's measured-fast body, verbatim (own ticket slot).
// Persistent 1024 blocks, grid-stride, mu copied from ws into LDS once,
// finalize fused into the LAST block. 4 blocks/CU.
// ---------------------------------------------------------------------------
__global__ __launch_bounds__(BLK, 4) void k_var(
    const float4* __restrict__ x4, const int4* __restrict__ t4,
    float* __restrict__ ws, float* __restrict__ out)
{
    __shared__ float s_mu[N_ * C_ * MUP];   // 1280 floats: both batches
    __shared__ float s_aux[8];
    __shared__ unsigned s_flag;

    float* gvar = ws + WS_VAR;
    const int bid = blockIdx.x, tid = threadIdx.x;
    const int lane = tid & 63, wid = tid >> 6;

    // prologue: copy the precomputed mu table (means + weights) into LDS
    {
        const float* mu = ws + WS_MU;
        for (int i = tid; i < N_ * C_ * MUP; i += BLK) s_mu[i] = mu[i];
    }
    __syncthreads();

    float va0 = 0.f, va1 = 0.f;
    for (int g = bid * BLK + tid; g < N_ * V4_; g += GV * BLK) {
        const int n  = (g >= V4_) ? 1 : 0;
        const int vg = g - n * V4_;
        const int4 t = t4[g];
        const float4* __restrict__ xr = x4 + (size_t)n * E_ * V4_ + vg;
        float4 xs[16];
        #pragma unroll
        for (int e = 0; e < 16; ++e) xs[e] = xr[(size_t)e * V4_];

        const int mb = n * (C_ * MUP);
        const int b0 = mb + t.x * MUP, b1 = mb + t.y * MUP;
        const int b2 = mb + t.z * MUP, b3 = mb + t.w * MUP;
        const float w0 = s_mu[b0 + 16], w1 = s_mu[b1 + 16];
        const float w2 = s_mu[b2 + 16], w3 = s_mu[b3 + 16];

        float d0 = 0.f, d1 = 0.f, d2 = 0.f, d3 = 0.f;
        #pragma unroll
        for (int e = 0; e < 16; ++e) {
            const float mu0 = s_mu[b0 + e];
            const float mu1 = s_mu[b1 + e];
            const float mu2 = s_mu[b2 + e];
            const float mu3 = s_mu[b3 + e];
            d0 += (xs[e].x - mu0) * (xs[e].x - mu0);
            d1 += (xs[e].y - mu1) * (xs[e].y - mu1);
            d2 += (xs[e].z - mu2) * (xs[e].z - mu2);
            d3 += (xs[e].w - mu3) * (xs[e].w - mu3);
        }
        const float h0 = fmaxf(sqrtf(d0) - DELTA_VAR, 0.f);
        const float h1 = fmaxf(sqrtf(d1) - DELTA_VAR, 0.f);
        const float h2 = fmaxf(sqrtf(d2) - DELTA_VAR, 0.f);
        const float h3 = fmaxf(sqrtf(d3) - DELTA_VAR, 0.f);
        const float vv = h0 * h0 * w0 + h1 * h1 * w1 + h2 * h2 * w2 + h3 * h3 * w3;
        va0 += (n == 0) ? vv : 0.f;
        va1 += (n == 0) ? 0.f : vv;
    }

    #pragma unroll
    for (int off = 32; off > 0; off >>= 1) {
        va0 += __shfl_down(va0, off, 64);
        va1 += __shfl_down(va1, off, 64);
    }
    if (lane == 0) { s_aux[wid * 2] = va0; s_aux[wid * 2 + 1] = va1; }
    __syncthreads();
    if (tid == 0) {
        const float t0 = s_aux[0] + s_aux[2] + s_aux[4] + s_aux[6];
        const float t1 = s_aux[1] + s_aux[3] + s_aux[5] + s_aux[7];
        const int kc = bid & (NCOPY - 1);
        unsafeAtomicAdd(&gvar[kc * N_ + 0], t0);
        unsafeAtomicAdd(&gvar[kc * N_ + 1], t1);
        __threadfence();             // my atomics visible before the ticket
        unsigned* tk = (unsigned*)(ws + WS_TK2);
        s_flag = (atomicAdd(tk, 1u) == (unsigned)(GV - 1)) ? 1u : 0u;
    }
    __syncthreads();

    // ---- finalize in the last block: repulsion + regularizer + assemble
    if (s_flag) {
        __threadfence();             // acquire: other blocks' gvar atomics
        float local = 0.f;
        if (tid < NCOPY * N_) local += gload(&gvar[tid]);   // all 16 entries

        for (int n = 0; n < N_; ++n) {
            const float* mu = s_mu + n * (C_ * MUP);
            if (tid < C_) {
                const int c = tid;
                float d2 = 0.f;
                #pragma unroll
                for (int e = 0; e < E_; ++e) {
                    const float m = mu[c * MUP + e];
                    d2 += m * m;
                }
                const float nm = d2 > 0.f ? sqrtf(d2) : 0.f;
                local += GAMMA * nm / (float)C_;
            }
            for (int t2 = tid; t2 < C_ * C_; t2 += BLK) {
                const int i = t2 >> 5, j = t2 & 31;
                if (i != j) {
                    float d2 = 0.f;
                    #pragma unroll
                    for (int e = 0; e < E_; ++e) {
                        const float diff = mu[i * MUP + e] - mu[j * MUP + e];
                        d2 += diff * diff;
                    }
                    const float d = d2 > 0.f ? sqrtf(d2) : 0.f;
                    const float h = fmaxf(2.0f * DELTA_DIST - d, 0.f);
                    local += (h * h) / (float)(C_ * (C_ - 1));
                }
            }
        }

        #pragma unroll
        for (int off = 32; off > 0; off >>= 1)
            local += __shfl_down(local, off, 64);
        if (lane == 0) s_aux[wid] = local;
        __syncthreads();
        if (tid == 0)
            out[0] = (s_aux[0] + s_aux[1] + s_aux[2] + s_aux[3]) / (float)N_;
    }
}

// ---------------------------------------------------------------------------
extern "C" void kernel_launch(void* const* d_in, const int* in_sizes, int n_in,
                              void* d_out, int out_size, void* d_ws, size_t ws_size,
                              hipStream_t stream) {
    const float4* x4 = (const float4*)d_in[0];
    const int4*   t4 = (const int4*)d_in[1];
    float* ws  = (float*)d_ws;
    float* out = (float*)d_out;

    hipMemsetAsync(d_ws, 0, WS_ZERO * sizeof(float), stream);

    sums_mfma<<<dim3(600, N_), BLK, 0, stream>>>(x4, t4, ws);
    k_var    <<<dim3(GV),      BLK, 0, stream>>>(x4, t4, ws, out);
}

// Round 7
// 416.422 us; speedup vs baseline: 1.1003x; 1.1003x over previous
//
#include <hip/hip_runtime.h>
#include <math.h>

// Problem constants (fixed by the reference's setup_inputs)
constexpr int N_  = 2;
constexpr int E_  = 16;
constexpr int C_  = 32;
constexpr int V_  = 48 * 160 * 160;   // 1,228,800 voxels per batch
constexpr int V4_ = V_ / 4;           // 307,200 float4 groups per batch
constexpr int BLK = 256;

constexpr float DELTA_VAR  = 0.5f;
constexpr float DELTA_DIST = 2.0f;
constexpr float GAMMA      = 0.001f;

// 8-way split accumulators (atomic decontention).
// ws floats: [0,8192) gsumT8[k][n][e][c] ; [8192,8704) gcnt8[k][n][c] ;
//            [8704,8720) gvar8[k][n] ; [8720] sums ticket ; [8721] var ticket ;
//            [8724,10004) mu[n][c][MUP]
constexpr int NCOPY     = 8;
constexpr int MUP       = 20;
constexpr int WS_SUMT   = 0;
constexpr int WS_CNT    = WS_SUMT + NCOPY * N_ * E_ * C_;   // 8192
constexpr int WS_VAR    = WS_CNT  + NCOPY * N_ * C_;        // 8704
constexpr int WS_TK1    = WS_VAR  + NCOPY * N_;             // 8720 (sums)
constexpr int WS_TK2    = WS_TK1 + 1;                       // 8721 (var)
constexpr int WS_MU     = WS_TK1 + 4;                       // 8724
constexpr int WS_ZERO   = WS_MU;                            // memset range (mu overwritten)

// sums geometry: 480 blocks/batch x 2560 voxels (5 tiles of 512).
// 960 blocks total at 4 blocks/CU capacity (33 KB LDS) -> SINGLE residency
// round on 240 of 256 CUs (R4/R5's 1200-block grid ran 1024 + ragged 176).
constexpr int SB_PB  = 480;           // sums blocks per batch
constexpr int VPB_   = V_ / SB_PB;    // 2560 voxels per block
constexpr int NT_    = VPB_ / 512;    // 5 tiles
constexpr int GS_TOT = SB_PB * N_;    // 960 (ticket target)
constexpr int GV     = 1024;          // variance grid: persistent, 4 blocks/CU

using short8 = __attribute__((ext_vector_type(8))) short;
using f32x4  = __attribute__((ext_vector_type(4))) float;

__device__ __forceinline__ unsigned short f2bf(float f) {
    unsigned u = __float_as_uint(f);
    return (unsigned short)((u + 0x7FFFu + ((u >> 16) & 1u)) >> 16);
}
__device__ __forceinline__ unsigned packlab(int4 t) {
    return (unsigned)t.x | ((unsigned)t.y << 8) | ((unsigned)t.z << 16) | ((unsigned)t.w << 24);
}
// agent-scope (device-coherent) load: reads values written by other blocks'
// device-scope atomics in the SAME kernel, bypassing possibly-stale L1/L2.
__device__ __forceinline__ float gload(const float* p) {
    return __hip_atomic_load(p, __ATOMIC_RELAXED, __HIP_MEMORY_SCOPE_AGENT);
}

// ---------------------------------------------------------------------------
// Kernel 1: MFMA segmented sums + counts — R4/R5-proven staged pipeline
// (double-buffered LDS, register prefetch, ONE lgkm-only barrier per tile),
// regeared to 5 tiles/block for single-round residency. LAST block (ticket)
// builds the mu table. grid = (480, N), block = 256 (4 waves).
// ---------------------------------------------------------------------------
constexpr int XPAD = 520;   // bf16 row stride for the 512-voxel tile
__global__ __launch_bounds__(BLK) void sums_mfma(
    const float4* __restrict__ x4, const int4* __restrict__ t4,
    float* __restrict__ ws)
{
    __shared__ unsigned short s_xb[2][E_ * XPAD];   // 33,280 B -> 4 blocks/CU
    __shared__ unsigned s_flag;

    const int n     = blockIdx.y;
    const int gtile = blockIdx.x * VPB_;
    const int tid   = threadIdx.x;
    const int lane  = tid & 63;
    const int wid   = tid >> 6;
    const int myc   = lane & 15;
    const int quad  = lane >> 4;

    const short one = (short)0x3F80;
    short8 A_ones = {one, one, one, one, one, one, one, one};

    f32x4 acc_lo = {0.f,0.f,0.f,0.f}, acc_hi = {0.f,0.f,0.f,0.f};
    f32x4 cnt_lo = {0.f,0.f,0.f,0.f}, cnt_hi = {0.f,0.f,0.f,0.f};

    // prologue: tile 0 loads
    float4 R[8];
    {
        const int tb4 = gtile >> 2;
        #pragma unroll
        for (int k = 0; k < 8; ++k) {
            const int i = k * BLK + tid, e = i >> 7, v4 = i & 127;
            R[k] = x4[((size_t)(n * E_ + e)) * V4_ + tb4 + v4];
        }
    }

    #pragma unroll
    for (int t = 0; t < NT_; ++t) {
        const int tbase4 = (gtile + t * 512) >> 2;
        unsigned short* buf = s_xb[t & 1];

        // convert + LDS stage (bf16)
        #pragma unroll
        for (int k = 0; k < 8; ++k) {
            const int i = k * BLK + tid, e = i >> 7, v4 = i & 127;
            uint2 p;
            p.x = (unsigned)f2bf(R[k].x) | ((unsigned)f2bf(R[k].y) << 16);
            p.y = (unsigned)f2bf(R[k].z) | ((unsigned)f2bf(R[k].w) << 16);
            *(uint2*)&buf[e * XPAD + v4 * 4] = p;
        }
        // labels for this tile FIRST (older vmem ops than the prefetch)
        const int wbase = wid * 128;
        int4 P[4], Q[4];
        #pragma unroll
        for (int s = 0; s < 4; ++s) {
            const int b4 = tbase4 + ((wbase + s * 32 + quad * 8) >> 2);
            P[s] = t4[(size_t)n * V4_ + b4];
            Q[s] = t4[(size_t)n * V4_ + b4 + 1];
        }
        // prefetch next tile — stays in flight across the raw barrier
        if (t + 1 < NT_) {
            const int nb4 = (gtile + (t + 1) * 512) >> 2;
            #pragma unroll
            for (int k = 0; k < 8; ++k) {
                const int i = k * BLK + tid, e = i >> 7, v4 = i & 127;
                R[k] = x4[((size_t)(n * E_ + e)) * V4_ + nb4 + v4];
            }
        }

        // lgkm-only barrier: orders ds_writes without draining vmcnt
        __builtin_amdgcn_sched_barrier(0);
        asm volatile("s_waitcnt lgkmcnt(0)");
        __builtin_amdgcn_s_barrier();
        __builtin_amdgcn_sched_barrier(0);

        // MFMA phase: 4 K-steps of 32 voxels over this wave's 128-voxel strip
        #pragma unroll
        for (int s = 0; s < 4; ++s) {
            const int lvb = wbase + s * 32;
            const short8 A = *(const short8*)&buf[myc * XPAD + lvb + quad * 8];
            const unsigned la = packlab(P[s]), lb2 = packlab(Q[s]);
            short8 Blo, Bhi;
            #pragma unroll
            for (int j = 0; j < 4; ++j) {
                const int c0 = (la  >> (8 * j)) & 255;
                const int c1 = (lb2 >> (8 * j)) & 255;
                Blo[j]     = (c0 == myc)      ? one : (short)0;
                Bhi[j]     = (c0 == myc + 16) ? one : (short)0;
                Blo[4 + j] = (c1 == myc)      ? one : (short)0;
                Bhi[4 + j] = (c1 == myc + 16) ? one : (short)0;
            }
            acc_lo = __builtin_amdgcn_mfma_f32_16x16x32_bf16(A,      Blo, acc_lo, 0, 0, 0);
            acc_hi = __builtin_amdgcn_mfma_f32_16x16x32_bf16(A,      Bhi, acc_hi, 0, 0, 0);
            cnt_lo = __builtin_amdgcn_mfma_f32_16x16x32_bf16(A_ones, Blo, cnt_lo, 0, 0, 0);
            cnt_hi = __builtin_amdgcn_mfma_f32_16x16x32_bf16(A_ones, Bhi, cnt_hi, 0, 0, 0);
        }
    }

    // ---- epilogue: cross-wave LDS reduce. NT_=5 is odd -> last MFMA tile
    // read buffer 0, so barrier BEFORE overlaying s_red on it.
    __syncthreads();
    float* s_red = (float*)&s_xb[0][0];   // 2048 sums + 128 counts
    #pragma unroll
    for (int r = 0; r < 4; ++r) {
        s_red[wid * 512 + lane * 8 + r]     = acc_lo[r];
        s_red[wid * 512 + lane * 8 + 4 + r] = acc_hi[r];
    }
    if (quad == 0) {
        s_red[2048 + wid * 32 + myc]      = cnt_lo[0];
        s_red[2048 + wid * 32 + myc + 16] = cnt_hi[0];
    }
    __syncthreads();

    const int kc = blockIdx.x & (NCOPY - 1);
    float* gsumT = ws + WS_SUMT + kc * (N_ * E_ * C_);
    float* gcntk = ws + WS_CNT  + kc * (N_ * C_);
    #pragma unroll
    for (int u = 0; u < 2; ++u) {
        const int combo = tid * 2 + u;              // 0..511
        const int l = combo >> 3, k = combo & 7;
        const int e = (l >> 4) * 4 + (k & 3);
        const int c = (l & 15) + 16 * (k >> 2);
        const float v = s_red[combo] + s_red[512 + combo]
                      + s_red[1024 + combo] + s_red[1536 + combo];
        unsafeAtomicAdd(&gsumT[(n * E_ + e) * C_ + c], v);
    }
    if (tid < C_) {
        const float v = s_red[2048 + tid] + s_red[2048 + 32 + tid]
                      + s_red[2048 + 64 + tid] + s_red[2048 + 96 + tid];
        unsafeAtomicAdd(&gcntk[n * C_ + tid], v);
    }

    // ---- ticket: LAST block builds the mu table (means + hinge weights)
    __threadfence();                 // my atomics globally visible
    __syncthreads();
    if (tid == 0) {
        unsigned* tk = (unsigned*)(ws + WS_TK1);
        s_flag = (atomicAdd(tk, 1u) == (unsigned)(GS_TOT - 1)) ? 1u : 0u;
    }
    __syncthreads();
    if (s_flag) {
        __threadfence();             // acquire: other blocks' atomics
        const float* gS = ws + WS_SUMT;
        const float* gC = ws + WS_CNT;
        float*       mu = ws + WS_MU;
        for (int i = tid; i < N_ * C_ * E_; i += BLK) {
            const int n2 = i >> 9;            // C_*E_ = 512
            const int r  = i & 511;
            const int c  = r >> 4, e = r & 15;
            float s = 0.f, cc = 0.f;
            #pragma unroll
            for (int k = 0; k < NCOPY; ++k) {
                s  += gload(&gS[k * (N_ * E_ * C_) + (n2 * E_ + e) * C_ + c]);
                cc += gload(&gC[k * (N_ * C_) + n2 * C_ + c]);
            }
            mu[(n2 * C_ + c) * MUP + e] = s / cc;
            if (e == 0) mu[(n2 * C_ + c) * MUP + 16] = 1.0f / (cc * (float)C_);
        }
    }
}

// ---------------------------------------------------------------------------
// Kernel 2: variance — R5's measured-fast body, verbatim (own ticket slot).
// Persistent 1024 blocks, grid-stride, mu copied from ws into LDS once,
// finalize fused into the LAST block. 4 blocks/CU.
// ---------------------------------------------------------------------------
__global__ __launch_bounds__(BLK, 4) void k_var(
    const float4* __restrict__ x4, const int4* __restrict__ t4,
    float* __restrict__ ws, float* __restrict__ out)
{
    __shared__ float s_mu[N_ * C_ * MUP];   // 1280 floats: both batches
    __shared__ float s_aux[8];
    __shared__ unsigned s_flag;

    float* gvar = ws + WS_VAR;
    const int bid = blockIdx.x, tid = threadIdx.x;
    const int lane = tid & 63, wid = tid >> 6;

    // prologue: copy the precomputed mu table (means + weights) into LDS
    {
        const float* mu = ws + WS_MU;
        for (int i = tid; i < N_ * C_ * MUP; i += BLK) s_mu[i] = mu[i];
    }
    __syncthreads();

    float va0 = 0.f, va1 = 0.f;
    for (int g = bid * BLK + tid; g < N_ * V4_; g += GV * BLK) {
        const int n  = (g >= V4_) ? 1 : 0;
        const int vg = g - n * V4_;
        const int4 t = t4[g];
        const float4* __restrict__ xr = x4 + (size_t)n * E_ * V4_ + vg;
        float4 xs[16];
        #pragma unroll
        for (int e = 0; e < 16; ++e) xs[e] = xr[(size_t)e * V4_];

        const int mb = n * (C_ * MUP);
        const int b0 = mb + t.x * MUP, b1 = mb + t.y * MUP;
        const int b2 = mb + t.z * MUP, b3 = mb + t.w * MUP;
        const float w0 = s_mu[b0 + 16], w1 = s_mu[b1 + 16];
        const float w2 = s_mu[b2 + 16], w3 = s_mu[b3 + 16];

        float d0 = 0.f, d1 = 0.f, d2 = 0.f, d3 = 0.f;
        #pragma unroll
        for (int e = 0; e < 16; ++e) {
            const float mu0 = s_mu[b0 + e];
            const float mu1 = s_mu[b1 + e];
            const float mu2 = s_mu[b2 + e];
            const float mu3 = s_mu[b3 + e];
            d0 += (xs[e].x - mu0) * (xs[e].x - mu0);
            d1 += (xs[e].y - mu1) * (xs[e].y - mu1);
            d2 += (xs[e].z - mu2) * (xs[e].z - mu2);
            d3 += (xs[e].w - mu3) * (xs[e].w - mu3);
        }
        const float h0 = fmaxf(sqrtf(d0) - DELTA_VAR, 0.f);
        const float h1 = fmaxf(sqrtf(d1) - DELTA_VAR, 0.f);
        const float h2 = fmaxf(sqrtf(d2) - DELTA_VAR, 0.f);
        const float h3 = fmaxf(sqrtf(d3) - DELTA_VAR, 0.f);
        const float vv = h0 * h0 * w0 + h1 * h1 * w1 + h2 * h2 * w2 + h3 * h3 * w3;
        va0 += (n == 0) ? vv : 0.f;
        va1 += (n == 0) ? 0.f : vv;
    }

    #pragma unroll
    for (int off = 32; off > 0; off >>= 1) {
        va0 += __shfl_down(va0, off, 64);
        va1 += __shfl_down(va1, off, 64);
    }
    if (lane == 0) { s_aux[wid * 2] = va0; s_aux[wid * 2 + 1] = va1; }
    __syncthreads();
    if (tid == 0) {
        const float t0 = s_aux[0] + s_aux[2] + s_aux[4] + s_aux[6];
        const float t1 = s_aux[1] + s_aux[3] + s_aux[5] + s_aux[7];
        const int kc = bid & (NCOPY - 1);
        unsafeAtomicAdd(&gvar[kc * N_ + 0], t0);
        unsafeAtomicAdd(&gvar[kc * N_ + 1], t1);
        __threadfence();             // my atomics visible before the ticket
        unsigned* tk = (unsigned*)(ws + WS_TK2);
        s_flag = (atomicAdd(tk, 1u) == (unsigned)(GV - 1)) ? 1u : 0u;
    }
    __syncthreads();

    // ---- finalize in the last block: repulsion + regularizer + assemble
    if (s_flag) {
        __threadfence();             // acquire: other blocks' gvar atomics
        float local = 0.f;
        if (tid < NCOPY * N_) local += gload(&gvar[tid]);   // all 16 entries

        for (int n = 0; n < N_; ++n) {
            const float* mu = s_mu + n * (C_ * MUP);
            if (tid < C_) {
                const int c = tid;
                float d2 = 0.f;
                #pragma unroll
                for (int e = 0; e < E_; ++e) {
                    const float m = mu[c * MUP + e];
                    d2 += m * m;
                }
                const float nm = d2 > 0.f ? sqrtf(d2) : 0.f;
                local += GAMMA * nm / (float)C_;
            }
            for (int t2 = tid; t2 < C_ * C_; t2 += BLK) {
                const int i = t2 >> 5, j = t2 & 31;
                if (i != j) {
                    float d2 = 0.f;
                    #pragma unroll
                    for (int e = 0; e < E_; ++e) {
                        const float diff = mu[i * MUP + e] - mu[j * MUP + e];
                        d2 += diff * diff;
                    }
                    const float d = d2 > 0.f ? sqrtf(d2) : 0.f;
                    const float h = fmaxf(2.0f * DELTA_DIST - d, 0.f);
                    local += (h * h) / (float)(C_ * (C_ - 1));
                }
            }
        }

        #pragma unroll
        for (int off = 32; off > 0; off >>= 1)
            local += __shfl_down(local, off, 64);
        if (lane == 0) s_aux[wid] = local;
        __syncthreads();
        if (tid == 0)
            out[0] = (s_aux[0] + s_aux[1] + s_aux[2] + s_aux[3]) / (float)N_;
    }
}

// ---------------------------------------------------------------------------
extern "C" void kernel_launch(void* const* d_in, const int* in_sizes, int n_in,
                              void* d_out, int out_size, void* d_ws, size_t ws_size,
                              hipStream_t stream) {
    const float4* x4 = (const float4*)d_in[0];
    const int4*   t4 = (const int4*)d_in[1];
    float* ws  = (float*)d_ws;
    float* out = (float*)d_out;

    hipMemsetAsync(d_ws, 0, WS_ZERO * sizeof(float), stream);

    sums_mfma<<<dim3(SB_PB, N_), BLK, 0, stream>>>(x4, t4, ws);
    k_var    <<<dim3(GV),        BLK, 0, stream>>>(x4, t4, ws, out);
}

// Round 8
// 288.742 us; speedup vs baseline: 1.5869x; 1.4422x over previous
//
#include <hip/hip_runtime.h>
#include <math.h>

// Problem constants (fixed by the reference's setup_inputs)
constexpr int N_  = 2;
constexpr int E_  = 16;
constexpr int C_  = 32;
constexpr int V_  = 48 * 160 * 160;   // 1,228,800 voxels per batch
constexpr int V4_ = V_ / 4;           // 307,200 float4 groups per batch
constexpr int BLK = 256;

constexpr float DELTA_VAR  = 0.5f;
constexpr float DELTA_DIST = 2.0f;
constexpr float GAMMA      = 0.001f;

// 8-way split accumulators (atomic decontention).
// ws floats: [0,8192) gsumT8[k][n][e][c] ; [8192,8704) gcnt8[k][n][c] ;
//            [8704,8720) gvar8[k][n] ; [8724,10004) mu[n][c][MUP]
constexpr int NCOPY     = 8;
constexpr int MUP       = 20;
constexpr int WS_SUMT   = 0;
constexpr int WS_CNT    = WS_SUMT + NCOPY * N_ * E_ * C_;   // 8192
constexpr int WS_VAR    = WS_CNT  + NCOPY * N_ * C_;        // 8704
constexpr int WS_MU     = WS_VAR  + NCOPY * N_ + 4;         // 8724
constexpr int WS_ZERO   = WS_VAR  + NCOPY * N_;             // memset range (mu overwritten)

constexpr int GV = 1024;              // variance grid: persistent, 4 blocks/CU

using short8 = __attribute__((ext_vector_type(8))) short;
using f32x4  = __attribute__((ext_vector_type(4))) float;

__device__ __forceinline__ unsigned short f2bf(float f) {
    unsigned u = __float_as_uint(f);
    return (unsigned short)((u + 0x7FFFu + ((u >> 16) & 1u)) >> 16);
}
__device__ __forceinline__ unsigned packlab(int4 t) {
    return (unsigned)t.x | ((unsigned)t.y << 8) | ((unsigned)t.z << 16) | ((unsigned)t.w << 24);
}

// ---------------------------------------------------------------------------
// Kernel 1: MFMA segmented sums + counts — BYTE-IDENTICAL to R1's measured-
// best version. grid = (600, N), block = 256 (4 waves), 2048 voxels/block.
// Register prefetch, double-buffered LDS, ONE lgkm-only barrier per tile.
// NO ticket/fence tail (every ticket-in-sums variant measured slow).
// ---------------------------------------------------------------------------
constexpr int XPAD = 520;   // bf16 row stride for the 512-voxel tile
__global__ __launch_bounds__(BLK) void sums_mfma(
    const float4* __restrict__ x4, const int4* __restrict__ t4,
    float* __restrict__ ws)
{
    __shared__ unsigned short s_xb[2][E_ * XPAD];

    const int n     = blockIdx.y;
    const int gtile = blockIdx.x * 2048;
    const int tid   = threadIdx.x;
    const int lane  = tid & 63;
    const int wid   = tid >> 6;
    const int myc   = lane & 15;
    const int quad  = lane >> 4;

    const short one = (short)0x3F80;
    short8 A_ones = {one, one, one, one, one, one, one, one};

    f32x4 acc_lo = {0.f,0.f,0.f,0.f}, acc_hi = {0.f,0.f,0.f,0.f};
    f32x4 cnt_lo = {0.f,0.f,0.f,0.f}, cnt_hi = {0.f,0.f,0.f,0.f};

    // prologue: tile 0 loads
    float4 R[8];
    {
        const int tb4 = gtile >> 2;
        #pragma unroll
        for (int k = 0; k < 8; ++k) {
            const int i = k * BLK + tid, e = i >> 7, v4 = i & 127;
            R[k] = x4[((size_t)(n * E_ + e)) * V4_ + tb4 + v4];
        }
    }

    for (int t = 0; t < 4; ++t) {
        const int tbase4 = (gtile + t * 512) >> 2;
        unsigned short* buf = s_xb[t & 1];

        // convert + LDS stage (bf16)
        #pragma unroll
        for (int k = 0; k < 8; ++k) {
            const int i = k * BLK + tid, e = i >> 7, v4 = i & 127;
            uint2 p;
            p.x = (unsigned)f2bf(R[k].x) | ((unsigned)f2bf(R[k].y) << 16);
            p.y = (unsigned)f2bf(R[k].z) | ((unsigned)f2bf(R[k].w) << 16);
            *(uint2*)&buf[e * XPAD + v4 * 4] = p;
        }
        // prefetch next tile — stays in flight across the raw barrier
        if (t < 3) {
            const int nb4 = (gtile + (t + 1) * 512) >> 2;
            #pragma unroll
            for (int k = 0; k < 8; ++k) {
                const int i = k * BLK + tid, e = i >> 7, v4 = i & 127;
                R[k] = x4[((size_t)(n * E_ + e)) * V4_ + nb4 + v4];
            }
        }
        // labels for this tile's MFMA phase — issued before the barrier
        const int wbase = wid * 128;
        int4 P[4], Q[4];
        #pragma unroll
        for (int s = 0; s < 4; ++s) {
            const int b4 = tbase4 + ((wbase + s * 32 + quad * 8) >> 2);
            P[s] = t4[(size_t)n * V4_ + b4];
            Q[s] = t4[(size_t)n * V4_ + b4 + 1];
        }

        // lgkm-only barrier: orders ds_writes without draining vmcnt
        __builtin_amdgcn_sched_barrier(0);
        asm volatile("s_waitcnt lgkmcnt(0)");
        __builtin_amdgcn_s_barrier();
        __builtin_amdgcn_sched_barrier(0);

        // MFMA phase: 4 K-steps of 32 voxels over this wave's 128-voxel strip
        #pragma unroll
        for (int s = 0; s < 4; ++s) {
            const int lvb = wbase + s * 32;
            const short8 A = *(const short8*)&buf[myc * XPAD + lvb + quad * 8];
            const unsigned la = packlab(P[s]), lb2 = packlab(Q[s]);
            short8 Blo, Bhi;
            #pragma unroll
            for (int j = 0; j < 4; ++j) {
                const int c0 = (la  >> (8 * j)) & 255;
                const int c1 = (lb2 >> (8 * j)) & 255;
                Blo[j]     = (c0 == myc)      ? one : (short)0;
                Bhi[j]     = (c0 == myc + 16) ? one : (short)0;
                Blo[4 + j] = (c1 == myc)      ? one : (short)0;
                Bhi[4 + j] = (c1 == myc + 16) ? one : (short)0;
            }
            acc_lo = __builtin_amdgcn_mfma_f32_16x16x32_bf16(A,      Blo, acc_lo, 0, 0, 0);
            acc_hi = __builtin_amdgcn_mfma_f32_16x16x32_bf16(A,      Bhi, acc_hi, 0, 0, 0);
            cnt_lo = __builtin_amdgcn_mfma_f32_16x16x32_bf16(A_ones, Blo, cnt_lo, 0, 0, 0);
            cnt_hi = __builtin_amdgcn_mfma_f32_16x16x32_bf16(A_ones, Bhi, cnt_hi, 0, 0, 0);
        }
    }

    // ---- epilogue: cross-wave LDS reduce, then 512 (+32) atomics per BLOCK
    // into one of 8 split copies. Buffer-0 overlay safe: last tile read buf 1.
    float* s_red = (float*)&s_xb[0][0];   // 2048 sums + 128 counts
    #pragma unroll
    for (int r = 0; r < 4; ++r) {
        s_red[wid * 512 + lane * 8 + r]     = acc_lo[r];
        s_red[wid * 512 + lane * 8 + 4 + r] = acc_hi[r];
    }
    if (quad == 0) {
        s_red[2048 + wid * 32 + myc]      = cnt_lo[0];
        s_red[2048 + wid * 32 + myc + 16] = cnt_hi[0];
    }
    __syncthreads();

    const int kc = blockIdx.x & (NCOPY - 1);
    float* gsumT = ws + WS_SUMT + kc * (N_ * E_ * C_);
    float* gcntk = ws + WS_CNT  + kc * (N_ * C_);
    #pragma unroll
    for (int u = 0; u < 2; ++u) {
        const int combo = tid * 2 + u;              // 0..511
        const int l = combo >> 3, k = combo & 7;
        const int e = (l >> 4) * 4 + (k & 3);
        const int c = (l & 15) + 16 * (k >> 2);
        const float v = s_red[combo] + s_red[512 + combo]
                      + s_red[1024 + combo] + s_red[1536 + combo];
        unsafeAtomicAdd(&gsumT[(n * E_ + e) * C_ + c], v);
    }
    if (tid < C_) {
        const float v = s_red[2048 + tid] + s_red[2048 + 32 + tid]
                      + s_red[2048 + 64 + tid] + s_red[2048 + 96 + tid];
        unsafeAtomicAdd(&gcntk[n * C_ + tid], v);
    }
}

// ---------------------------------------------------------------------------
// Kernel 2: tiny single-block mu build (means + hinge weights into ws).
// Kernel-boundary ordering makes the sums atomics coherent — plain loads.
// ---------------------------------------------------------------------------
__global__ __launch_bounds__(BLK) void k_mu(float* __restrict__ ws)
{
    const float* gS = ws + WS_SUMT;
    const float* gC = ws + WS_CNT;
    float*       mu = ws + WS_MU;
    const int tid = threadIdx.x;
    for (int i = tid; i < N_ * C_ * E_; i += BLK) {
        const int n2 = i >> 9;            // C_*E_ = 512
        const int r  = i & 511;
        const int c  = r >> 4, e = r & 15;
        float s = 0.f, cc = 0.f;
        #pragma unroll
        for (int k = 0; k < NCOPY; ++k) {
            s  += gS[k * (N_ * E_ * C_) + (n2 * E_ + e) * C_ + c];
            cc += gC[k * (N_ * C_) + n2 * C_ + c];
        }
        mu[(n2 * C_ + c) * MUP + e] = s / cc;
        if (e == 0) mu[(n2 * C_ + c) * MUP + 16] = 1.0f / (cc * (float)C_);
    }
}

// ---------------------------------------------------------------------------
// Kernel 3: variance — persistent 1024 blocks, grid-stride, mu copied from ws
// into LDS once. NO ticket, NO fence: ends after two gvar atomics per block.
// ---------------------------------------------------------------------------
__global__ __launch_bounds__(BLK, 4) void k_var(
    const float4* __restrict__ x4, const int4* __restrict__ t4,
    float* __restrict__ ws)
{
    __shared__ float s_mu[N_ * C_ * MUP];   // 1280 floats: both batches
    __shared__ float s_aux[8];

    float* gvar = ws + WS_VAR;
    const int bid = blockIdx.x, tid = threadIdx.x;
    const int lane = tid & 63, wid = tid >> 6;

    // prologue: copy the precomputed mu table (means + weights) into LDS
    {
        const float* mu = ws + WS_MU;
        for (int i = tid; i < N_ * C_ * MUP; i += BLK) s_mu[i] = mu[i];
    }
    __syncthreads();

    float va0 = 0.f, va1 = 0.f;
    for (int g = bid * BLK + tid; g < N_ * V4_; g += GV * BLK) {
        const int n  = (g >= V4_) ? 1 : 0;
        const int vg = g - n * V4_;
        const int4 t = t4[g];
        const float4* __restrict__ xr = x4 + (size_t)n * E_ * V4_ + vg;
        float4 xs[16];
        #pragma unroll
        for (int e = 0; e < 16; ++e) xs[e] = xr[(size_t)e * V4_];

        const int mb = n * (C_ * MUP);
        const int b0 = mb + t.x * MUP, b1 = mb + t.y * MUP;
        const int b2 = mb + t.z * MUP, b3 = mb + t.w * MUP;
        const float w0 = s_mu[b0 + 16], w1 = s_mu[b1 + 16];
        const float w2 = s_mu[b2 + 16], w3 = s_mu[b3 + 16];

        float d0 = 0.f, d1 = 0.f, d2 = 0.f, d3 = 0.f;
        #pragma unroll
        for (int e = 0; e < 16; ++e) {
            const float mu0 = s_mu[b0 + e];
            const float mu1 = s_mu[b1 + e];
            const float mu2 = s_mu[b2 + e];
            const float mu3 = s_mu[b3 + e];
            d0 += (xs[e].x - mu0) * (xs[e].x - mu0);
            d1 += (xs[e].y - mu1) * (xs[e].y - mu1);
            d2 += (xs[e].z - mu2) * (xs[e].z - mu2);
            d3 += (xs[e].w - mu3) * (xs[e].w - mu3);
        }
        const float h0 = fmaxf(sqrtf(d0) - DELTA_VAR, 0.f);
        const float h1 = fmaxf(sqrtf(d1) - DELTA_VAR, 0.f);
        const float h2 = fmaxf(sqrtf(d2) - DELTA_VAR, 0.f);
        const float h3 = fmaxf(sqrtf(d3) - DELTA_VAR, 0.f);
        const float vv = h0 * h0 * w0 + h1 * h1 * w1 + h2 * h2 * w2 + h3 * h3 * w3;
        va0 += (n == 0) ? vv : 0.f;
        va1 += (n == 0) ? 0.f : vv;
    }

    #pragma unroll
    for (int off = 32; off > 0; off >>= 1) {
        va0 += __shfl_down(va0, off, 64);
        va1 += __shfl_down(va1, off, 64);
    }
    if (lane == 0) { s_aux[wid * 2] = va0; s_aux[wid * 2 + 1] = va1; }
    __syncthreads();
    if (tid == 0) {
        const float t0 = s_aux[0] + s_aux[2] + s_aux[4] + s_aux[6];
        const float t1 = s_aux[1] + s_aux[3] + s_aux[5] + s_aux[7];
        const int kc = bid & (NCOPY - 1);
        unsafeAtomicAdd(&gvar[kc * N_ + 0], t0);
        unsafeAtomicAdd(&gvar[kc * N_ + 1], t1);
    }
}

// ---------------------------------------------------------------------------
// Kernel 4: finalize (single block) — reads the precomputed mu table and the
// 16 gvar entries; repulsion + regularizer + assemble.
// ---------------------------------------------------------------------------
__global__ __launch_bounds__(BLK) void k_fin(
    const float* __restrict__ ws, float* __restrict__ out)
{
    __shared__ float s_mu[N_ * C_ * MUP];
    __shared__ float s_aux[4];

    const float* gvar = ws + WS_VAR;
    const int tid = threadIdx.x;
    const int lane = tid & 63, wid = tid >> 6;

    {
        const float* mu = ws + WS_MU;
        for (int i = tid; i < N_ * C_ * MUP; i += BLK) s_mu[i] = mu[i];
    }
    __syncthreads();

    float local = 0.f;
    if (tid < NCOPY * N_) local += gvar[tid];   // all 16 split variance sums

    for (int n = 0; n < N_; ++n) {
        const float* mu = s_mu + n * (C_ * MUP);
        if (tid < C_) {
            const int c = tid;
            float d2 = 0.f;
            #pragma unroll
            for (int e = 0; e < E_; ++e) {
                const float m = mu[c * MUP + e];
                d2 += m * m;
            }
            const float nm = d2 > 0.f ? sqrtf(d2) : 0.f;
            local += GAMMA * nm / (float)C_;
        }
        for (int t2 = tid; t2 < C_ * C_; t2 += BLK) {
            const int i = t2 >> 5, j = t2 & 31;
            if (i != j) {
                float d2 = 0.f;
                #pragma unroll
                for (int e = 0; e < E_; ++e) {
                    const float diff = mu[i * MUP + e] - mu[j * MUP + e];
                    d2 += diff * diff;
                }
                const float d = d2 > 0.f ? sqrtf(d2) : 0.f;
                const float h = fmaxf(2.0f * DELTA_DIST - d, 0.f);
                local += (h * h) / (float)(C_ * (C_ - 1));
            }
        }
    }

    #pragma unroll
    for (int off = 32; off > 0; off >>= 1)
        local += __shfl_down(local, off, 64);
    if (lane == 0) s_aux[wid] = local;
    __syncthreads();
    if (tid == 0)
        out[0] = (s_aux[0] + s_aux[1] + s_aux[2] + s_aux[3]) / (float)N_;
}

// ---------------------------------------------------------------------------
extern "C" void kernel_launch(void* const* d_in, const int* in_sizes, int n_in,
                              void* d_out, int out_size, void* d_ws, size_t ws_size,
                              hipStream_t stream) {
    const float4* x4 = (const float4*)d_in[0];
    const int4*   t4 = (const int4*)d_in[1];
    float* ws  = (float*)d_ws;
    float* out = (float*)d_out;

    hipMemsetAsync(d_ws, 0, WS_ZERO * sizeof(float), stream);

    sums_mfma<<<dim3(600, N_), BLK, 0, stream>>>(x4, t4, ws);
    k_mu     <<<1,             BLK, 0, stream>>>(ws);
    k_var    <<<dim3(GV),      BLK, 0, stream>>>(x4, t4, ws);
    k_fin    <<<1,             BLK, 0, stream>>>(ws, out);
}

// Round 9
// 287.631 us; speedup vs baseline: 1.5930x; 1.0039x over previous
//
#include <hip/hip_runtime.h>
#include <math.h>

// Problem constants (fixed by the reference's setup_inputs)
constexpr int N_  = 2;
constexpr int E_  = 16;
constexpr int C_  = 32;
constexpr int V_  = 48 * 160 * 160;   // 1,228,800 voxels per batch
constexpr int V4_ = V_ / 4;           // 307,200 float4 groups per batch
constexpr int BLK = 256;

constexpr float DELTA_VAR  = 0.5f;
constexpr float DELTA_DIST = 2.0f;
constexpr float GAMMA      = 0.001f;

// 8-way split accumulators (atomic decontention).
// ws floats: [0,8192) gsumT8[k][n][e][c] ; [8192,8704) gcnt8[k][n][c] ;
//            [8704,8720) gvar8[k][n] ; [8724,10004) mu[n][c][MUP]
constexpr int NCOPY     = 8;
constexpr int MUP       = 20;
constexpr int WS_SUMT   = 0;
constexpr int WS_CNT    = WS_SUMT + NCOPY * N_ * E_ * C_;   // 8192
constexpr int WS_VAR    = WS_CNT  + NCOPY * N_ * C_;        // 8704
constexpr int WS_MU     = WS_VAR  + NCOPY * N_ + 4;         // 8724
constexpr int WS_ZERO   = WS_VAR  + NCOPY * N_;             // memset range (mu overwritten)

constexpr int GV = 1024;              // variance grid: persistent, 4 blocks/CU

using short8 = __attribute__((ext_vector_type(8))) short;
using f32x4  = __attribute__((ext_vector_type(4))) float;

__device__ __forceinline__ unsigned short f2bf(float f) {
    unsigned u = __float_as_uint(f);
    return (unsigned short)((u + 0x7FFFu + ((u >> 16) & 1u)) >> 16);
}
__device__ __forceinline__ unsigned packlab(int4 t) {
    return (unsigned)t.x | ((unsigned)t.y << 8) | ((unsigned)t.z << 16) | ((unsigned)t.w << 24);
}

// ---------------------------------------------------------------------------
// Kernel 1: MFMA segmented sums + counts — R8 structure with ONE delta:
// labels are staged packed into LDS (512 B/tile, threads 0-127) instead of
// being read from global inside the MFMA phase. The MFMA phase then has ZERO
// vmem waits (labels come off the same lgkm barrier), and the x-prefetch
// stays in flight across the whole MFMA phase + barrier.
// grid = (600, N), block = 256 (4 waves), 2048 voxels per block.
// ---------------------------------------------------------------------------
constexpr int XPAD = 520;   // bf16 row stride for the 512-voxel tile
__global__ __launch_bounds__(BLK) void sums_mfma(
    const float4* __restrict__ x4, const int4* __restrict__ t4,
    float* __restrict__ ws)
{
    __shared__ unsigned short s_xb[2][E_ * XPAD];   // 33,280 B
    __shared__ unsigned s_lab[2][128];              // 1,024 B: packed labels

    const int n     = blockIdx.y;
    const int gtile = blockIdx.x * 2048;
    const int tid   = threadIdx.x;
    const int lane  = tid & 63;
    const int wid   = tid >> 6;
    const int myc   = lane & 15;
    const int quad  = lane >> 4;

    const short one = (short)0x3F80;
    short8 A_ones = {one, one, one, one, one, one, one, one};

    f32x4 acc_lo = {0.f,0.f,0.f,0.f}, acc_hi = {0.f,0.f,0.f,0.f};
    f32x4 cnt_lo = {0.f,0.f,0.f,0.f}, cnt_hi = {0.f,0.f,0.f,0.f};

    const int4* __restrict__ t4n = t4 + (size_t)n * V4_;

    // prologue: tile 0 loads (x for all threads; labels on threads 0-127)
    float4 R[8];
    int4   Lr = {0, 0, 0, 0};
    {
        const int tb4 = gtile >> 2;
        #pragma unroll
        for (int k = 0; k < 8; ++k) {
            const int i = k * BLK + tid, e = i >> 7, v4 = i & 127;
            R[k] = x4[((size_t)(n * E_ + e)) * V4_ + tb4 + v4];
        }
        if (tid < 128) Lr = t4n[tb4 + tid];
    }

    for (int t = 0; t < 4; ++t) {
        unsigned short* buf = s_xb[t & 1];
        unsigned*       lab = s_lab[t & 1];

        // convert + LDS stage (bf16 x-tile + packed labels)
        #pragma unroll
        for (int k = 0; k < 8; ++k) {
            const int i = k * BLK + tid, e = i >> 7, v4 = i & 127;
            uint2 p;
            p.x = (unsigned)f2bf(R[k].x) | ((unsigned)f2bf(R[k].y) << 16);
            p.y = (unsigned)f2bf(R[k].z) | ((unsigned)f2bf(R[k].w) << 16);
            *(uint2*)&buf[e * XPAD + v4 * 4] = p;
        }
        if (tid < 128) lab[tid] = packlab(Lr);

        // prefetch next tile — stays in flight across the raw barrier and
        // the ENTIRE MFMA phase (no vmem waits remain after the barrier)
        if (t < 3) {
            const int nb4 = (gtile + (t + 1) * 512) >> 2;
            #pragma unroll
            for (int k = 0; k < 8; ++k) {
                const int i = k * BLK + tid, e = i >> 7, v4 = i & 127;
                R[k] = x4[((size_t)(n * E_ + e)) * V4_ + nb4 + v4];
            }
            if (tid < 128) Lr = t4n[nb4 + tid];
        }

        // lgkm-only barrier: orders ds_writes without draining vmcnt
        __builtin_amdgcn_sched_barrier(0);
        asm volatile("s_waitcnt lgkmcnt(0)");
        __builtin_amdgcn_s_barrier();
        __builtin_amdgcn_sched_barrier(0);

        // MFMA phase: 4 K-steps of 32 voxels over this wave's 128-voxel strip.
        // Labels come from LDS (16-lane broadcast, conflict-free).
        const int wbase = wid * 128;
        #pragma unroll
        for (int s = 0; s < 4; ++s) {
            const int lvb = wbase + s * 32;
            const short8 A = *(const short8*)&buf[myc * XPAD + lvb + quad * 8];
            const uint2 lw = *(const uint2*)&lab[(lvb + quad * 8) >> 2];
            const unsigned la = lw.x, lb2 = lw.y;
            short8 Blo, Bhi;
            #pragma unroll
            for (int j = 0; j < 4; ++j) {
                const int c0 = (la  >> (8 * j)) & 255;
                const int c1 = (lb2 >> (8 * j)) & 255;
                Blo[j]     = (c0 == myc)      ? one : (short)0;
                Bhi[j]     = (c0 == myc + 16) ? one : (short)0;
                Blo[4 + j] = (c1 == myc)      ? one : (short)0;
                Bhi[4 + j] = (c1 == myc + 16) ? one : (short)0;
            }
            acc_lo = __builtin_amdgcn_mfma_f32_16x16x32_bf16(A,      Blo, acc_lo, 0, 0, 0);
            acc_hi = __builtin_amdgcn_mfma_f32_16x16x32_bf16(A,      Bhi, acc_hi, 0, 0, 0);
            cnt_lo = __builtin_amdgcn_mfma_f32_16x16x32_bf16(A_ones, Blo, cnt_lo, 0, 0, 0);
            cnt_hi = __builtin_amdgcn_mfma_f32_16x16x32_bf16(A_ones, Bhi, cnt_hi, 0, 0, 0);
        }
    }

    // ---- epilogue: cross-wave LDS reduce, then 512 (+32) atomics per BLOCK
    // into one of 8 split copies. Buffer-0 overlay safe: last tile read buf 1.
    float* s_red = (float*)&s_xb[0][0];   // 2048 sums + 128 counts
    #pragma unroll
    for (int r = 0; r < 4; ++r) {
        s_red[wid * 512 + lane * 8 + r]     = acc_lo[r];
        s_red[wid * 512 + lane * 8 + 4 + r] = acc_hi[r];
    }
    if (quad == 0) {
        s_red[2048 + wid * 32 + myc]      = cnt_lo[0];
        s_red[2048 + wid * 32 + myc + 16] = cnt_hi[0];
    }
    __syncthreads();

    const int kc = blockIdx.x & (NCOPY - 1);
    float* gsumT = ws + WS_SUMT + kc * (N_ * E_ * C_);
    float* gcntk = ws + WS_CNT  + kc * (N_ * C_);
    #pragma unroll
    for (int u = 0; u < 2; ++u) {
        const int combo = tid * 2 + u;              // 0..511
        const int l = combo >> 3, k = combo & 7;
        const int e = (l >> 4) * 4 + (k & 3);
        const int c = (l & 15) + 16 * (k >> 2);
        const float v = s_red[combo] + s_red[512 + combo]
                      + s_red[1024 + combo] + s_red[1536 + combo];
        unsafeAtomicAdd(&gsumT[(n * E_ + e) * C_ + c], v);
    }
    if (tid < C_) {
        const float v = s_red[2048 + tid] + s_red[2048 + 32 + tid]
                      + s_red[2048 + 64 + tid] + s_red[2048 + 96 + tid];
        unsafeAtomicAdd(&gcntk[n * C_ + tid], v);
    }
}

// ---------------------------------------------------------------------------
// Kernel 2: tiny single-block mu build (means + hinge weights into ws).
// Kernel-boundary ordering makes the sums atomics coherent — plain loads.
// ---------------------------------------------------------------------------
__global__ __launch_bounds__(BLK) void k_mu(float* __restrict__ ws)
{
    const float* gS = ws + WS_SUMT;
    const float* gC = ws + WS_CNT;
    float*       mu = ws + WS_MU;
    const int tid = threadIdx.x;
    for (int i = tid; i < N_ * C_ * E_; i += BLK) {
        const int n2 = i >> 9;            // C_*E_ = 512
        const int r  = i & 511;
        const int c  = r >> 4, e = r & 15;
        float s = 0.f, cc = 0.f;
        #pragma unroll
        for (int k = 0; k < NCOPY; ++k) {
            s  += gS[k * (N_ * E_ * C_) + (n2 * E_ + e) * C_ + c];
            cc += gC[k * (N_ * C_) + n2 * C_ + c];
        }
        mu[(n2 * C_ + c) * MUP + e] = s / cc;
        if (e == 0) mu[(n2 * C_ + c) * MUP + 16] = 1.0f / (cc * (float)C_);
    }
}

// ---------------------------------------------------------------------------
// Kernel 3: variance — persistent 1024 blocks, grid-stride, mu copied from ws
// into LDS once. NO ticket, NO fence: ends after two gvar atomics per block.
// ---------------------------------------------------------------------------
__global__ __launch_bounds__(BLK, 4) void k_var(
    const float4* __restrict__ x4, const int4* __restrict__ t4,
    float* __restrict__ ws)
{
    __shared__ float s_mu[N_ * C_ * MUP];   // 1280 floats: both batches
    __shared__ float s_aux[8];

    float* gvar = ws + WS_VAR;
    const int bid = blockIdx.x, tid = threadIdx.x;
    const int lane = tid & 63, wid = tid >> 6;

    // prologue: copy the precomputed mu table (means + weights) into LDS
    {
        const float* mu = ws + WS_MU;
        for (int i = tid; i < N_ * C_ * MUP; i += BLK) s_mu[i] = mu[i];
    }
    __syncthreads();

    float va0 = 0.f, va1 = 0.f;
    for (int g = bid * BLK + tid; g < N_ * V4_; g += GV * BLK) {
        const int n  = (g >= V4_) ? 1 : 0;
        const int vg = g - n * V4_;
        const int4 t = t4[g];
        const float4* __restrict__ xr = x4 + (size_t)n * E_ * V4_ + vg;
        float4 xs[16];
        #pragma unroll
        for (int e = 0; e < 16; ++e) xs[e] = xr[(size_t)e * V4_];

        const int mb = n * (C_ * MUP);
        const int b0 = mb + t.x * MUP, b1 = mb + t.y * MUP;
        const int b2 = mb + t.z * MUP, b3 = mb + t.w * MUP;
        const float w0 = s_mu[b0 + 16], w1 = s_mu[b1 + 16];
        const float w2 = s_mu[b2 + 16], w3 = s_mu[b3 + 16];

        float d0 = 0.f, d1 = 0.f, d2 = 0.f, d3 = 0.f;
        #pragma unroll
        for (int e = 0; e < 16; ++e) {
            const float mu0 = s_mu[b0 + e];
            const float mu1 = s_mu[b1 + e];
            const float mu2 = s_mu[b2 + e];
            const float mu3 = s_mu[b3 + e];
            d0 += (xs[e].x - mu0) * (xs[e].x - mu0);
            d1 += (xs[e].y - mu1) * (xs[e].y - mu1);
            d2 += (xs[e].z - mu2) * (xs[e].z - mu2);
            d3 += (xs[e].w - mu3) * (xs[e].w - mu3);
        }
        const float h0 = fmaxf(sqrtf(d0) - DELTA_VAR, 0.f);
        const float h1 = fmaxf(sqrtf(d1) - DELTA_VAR, 0.f);
        const float h2 = fmaxf(sqrtf(d2) - DELTA_VAR, 0.f);
        const float h3 = fmaxf(sqrtf(d3) - DELTA_VAR, 0.f);
        const float vv = h0 * h0 * w0 + h1 * h1 * w1 + h2 * h2 * w2 + h3 * h3 * w3;
        va0 += (n == 0) ? vv : 0.f;
        va1 += (n == 0) ? 0.f : vv;
    }

    #pragma unroll
    for (int off = 32; off > 0; off >>= 1) {
        va0 += __shfl_down(va0, off, 64);
        va1 += __shfl_down(va1, off, 64);
    }
    if (lane == 0) { s_aux[wid * 2] = va0; s_aux[wid * 2 + 1] = va1; }
    __syncthreads();
    if (tid == 0) {
        const float t0 = s_aux[0] + s_aux[2] + s_aux[4] + s_aux[6];
        const float t1 = s_aux[1] + s_aux[3] + s_aux[5] + s_aux[7];
        const int kc = bid & (NCOPY - 1);
        unsafeAtomicAdd(&gvar[kc * N_ + 0], t0);
        unsafeAtomicAdd(&gvar[kc * N_ + 1], t1);
    }
}

// ---------------------------------------------------------------------------
// Kernel 4: finalize (single block) — reads the precomputed mu table and the
// 16 gvar entries; repulsion + regularizer + assemble.
// ---------------------------------------------------------------------------
__global__ __launch_bounds__(BLK) void k_fin(
    const float* __restrict__ ws, float* __restrict__ out)
{
    __shared__ float s_mu[N_ * C_ * MUP];
    __shared__ float s_aux[4];

    const float* gvar = ws + WS_VAR;
    const int tid = threadIdx.x;
    const int lane = tid & 63, wid = tid >> 6;

    {
        const float* mu = ws + WS_MU;
        for (int i = tid; i < N_ * C_ * MUP; i += BLK) s_mu[i] = mu[i];
    }
    __syncthreads();

    float local = 0.f;
    if (tid < NCOPY * N_) local += gvar[tid];   // all 16 split variance sums

    for (int n = 0; n < N_; ++n) {
        const float* mu = s_mu + n * (C_ * MUP);
        if (tid < C_) {
            const int c = tid;
            float d2 = 0.f;
            #pragma unroll
            for (int e = 0; e < E_; ++e) {
                const float m = mu[c * MUP + e];
                d2 += m * m;
            }
            const float nm = d2 > 0.f ? sqrtf(d2) : 0.f;
            local += GAMMA * nm / (float)C_;
        }
        for (int t2 = tid; t2 < C_ * C_; t2 += BLK) {
            const int i = t2 >> 5, j = t2 & 31;
            if (i != j) {
                float d2 = 0.f;
                #pragma unroll
                for (int e = 0; e < E_; ++e) {
                    const float diff = mu[i * MUP + e] - mu[j * MUP + e];
                    d2 += diff * diff;
                }
                const float d = d2 > 0.f ? sqrtf(d2) : 0.f;
                const float h = fmaxf(2.0f * DELTA_DIST - d, 0.f);
                local += (h * h) / (float)(C_ * (C_ - 1));
            }
        }
    }

    #pragma unroll
    for (int off = 32; off > 0; off >>= 1)
        local += __shfl_down(local, off, 64);
    if (lane == 0) s_aux[wid] = local;
    __syncthreads();
    if (tid == 0)
        out[0] = (s_aux[0] + s_aux[1] + s_aux[2] + s_aux[3]) / (float)N_;
}

// ---------------------------------------------------------------------------
extern "C" void kernel_launch(void* const* d_in, const int* in_sizes, int n_in,
                              void* d_out, int out_size, void* d_ws, size_t ws_size,
                              hipStream_t stream) {
    const float4* x4 = (const float4*)d_in[0];
    const int4*   t4 = (const int4*)d_in[1];
    float* ws  = (float*)d_ws;
    float* out = (float*)d_out;

    hipMemsetAsync(d_ws, 0, WS_ZERO * sizeof(float), stream);

    sums_mfma<<<dim3(600, N_), BLK, 0, stream>>>(x4, t4, ws);
    k_mu     <<<1,             BLK, 0, stream>>>(ws);
    k_var    <<<dim3(GV),      BLK, 0, stream>>>(x4, t4, ws);
    k_fin    <<<1,             BLK, 0, stream>>>(ws, out);
}